// Round 1
// baseline (687.429 us; speedup 1.0000x reference)
//
#include <hip/hip_runtime.h>
#include <hip/hip_bf16.h>

typedef __hip_bfloat16 bf16;
typedef __attribute__((ext_vector_type(4))) float f32x4;
typedef __attribute__((ext_vector_type(8))) short bf16x8;

#define MFMA16(a,b,c) __builtin_amdgcn_mfma_f32_16x16x32_bf16((a),(b),(c),0,0,0)

static __device__ inline unsigned short bfbits(float f) {
  __hip_bfloat16 h = __float2bfloat16(f);
  union { __hip_bfloat16 h; unsigned short u; } u;
  u.h = h; return u.u;
}

// ---------------- weight transpose + bf16 (+ optional q-scale on first scaleN cols)
__global__ __launch_bounds__(256) void transpose_w(const float* __restrict__ src,
                                                   bf16* __restrict__ dst,
                                                   int N, int K, int scaleN, float scale) {
  int idx = blockIdx.x * 256 + threadIdx.x;
  if (idx >= N * K) return;
  int n = idx / K, k = idx - n * K;
  float v = src[(size_t)k * N + n];
  if (n < scaleN) v *= scale;
  dst[idx] = __float2bfloat16(v);
}

// ---------------- relative position bias table: biasT[h][n][m], n,m in [0,98)
__global__ __launch_bounds__(256) void bias_table(const float* __restrict__ rpb,
                                                  float* __restrict__ biasT) {
  int idx = blockIdx.x * 256 + threadIdx.x;
  if (idx >= 98 * 98) return;
  int nn = idx / 98, mm = idx - nn * 98;
  int ld = nn / 49, lrem = nn - ld * 49, lh = lrem / 7, lw = lrem - lh * 7;
  int md = mm / 49, mrem = mm - md * 49, mh = mrem / 7, mw = mrem - mh * 7;
  int rel = (ld - md + 1) * 169 + (lh - mh + 6) * 13 + (lw - mw + 6);
  #pragma unroll
  for (int h = 0; h < 8; ++h)
    biasT[h * 9604 + idx] = rpb[rel * 8 + h];
}

// ---------------- LayerNorm (one wave per token, 4 ch/lane).
// windowed=1: output rows are window-ordered (LN1 + roll + partition fused)
__global__ __launch_bounds__(256) void ln_k(const float* __restrict__ x,
                                            const float* __restrict__ g,
                                            const float* __restrict__ bias,
                                            bf16* __restrict__ out, int windowed) {
  const int wid = threadIdx.x >> 6, lane = threadIdx.x & 63;
  const int t = blockIdx.x * 4 + wid;   // destination row
  int src = t;
  if (windowed) {
    int widx = t / 98, n = t - widx * 98;
    int zd = widx >> 6, zh = (widx >> 3) & 7, zw = widx & 7;
    int ld = n / 49, rem = n - ld * 49, lh = rem / 7, lw = rem - lh * 7;
    int d = zd * 2 + ld, h = zh * 7 + lh, w = zw * 7 + lw;
    int dsrc = (d + 1) & 15;
    int hsrc = h + 3; if (hsrc >= 56) hsrc -= 56;
    int wsrc = w + 3; if (wsrc >= 56) wsrc -= 56;
    src = (dsrc * 56 + hsrc) * 56 + wsrc;
  }
  const float4 v = *(const float4*)(x + (size_t)src * 256 + lane * 4);
  float s1 = v.x + v.y + v.z + v.w;
  float s2 = v.x * v.x + v.y * v.y + v.z * v.z + v.w * v.w;
  #pragma unroll
  for (int d = 1; d < 64; d <<= 1) {
    s1 += __shfl_xor(s1, d);
    s2 += __shfl_xor(s2, d);
  }
  float mu = s1 * (1.f / 256.f);
  float var = s2 * (1.f / 256.f) - mu * mu;
  float rs = rsqrtf(var + 1e-5f);
  const float4 gv = *(const float4*)(g + lane * 4);
  const float4 bv = *(const float4*)(bias + lane * 4);
  ushort4 pk;
  pk.x = bfbits((v.x - mu) * rs * gv.x + bv.x);
  pk.y = bfbits((v.y - mu) * rs * gv.y + bv.y);
  pk.z = bfbits((v.z - mu) * rs * gv.z + bv.z);
  pk.w = bfbits((v.w - mu) * rs * gv.w + bv.w);
  *(ushort4*)((unsigned short*)out + (size_t)t * 256 + lane * 4) = pk;
}

// ---------------- GEMM: C = A[M x K]bf16 @ Bt[N x K]bf16^T + bias, fused epilogues
// EPI 0: scatter to qkv[3][512][8][98][32] (q-scale folded into Bt & bias here)
// EPI 1: proj -> window-reverse+unroll residual add with x -> x2 (fp32)
// EPI 2: exact GELU -> bf16 row-major stride 1024
// EPI 3: + x2 residual -> fp32 out row-major stride 256 (rows offset by mrow0)
template<int EPI>
__global__ __launch_bounds__(256) void gemm_k(const bf16* __restrict__ A,
                                              const bf16* __restrict__ Bt,
                                              const float* __restrict__ bias,
                                              int N, int K, int mrow0,
                                              bf16* __restrict__ out_bf,
                                              float* __restrict__ out_f,
                                              const float* __restrict__ add_f) {
  __shared__ bf16 As[128 * 32];
  __shared__ bf16 Bs[128 * 32];
  const int tid = threadIdx.x;
  const int wid = tid >> 6, lane = tid & 63;
  const int row0 = blockIdx.x * 128, col0 = blockIdx.y * 128;
  const int lrow = tid >> 2, lcol = (tid & 3) * 8;
  const int fr = lane & 15, kh = lane >> 4;
  const int wm = (wid >> 1) * 64, wn = (wid & 1) * 64;
  f32x4 zero4 = {0.f, 0.f, 0.f, 0.f};
  f32x4 acc[4][4];
  #pragma unroll
  for (int i = 0; i < 4; ++i)
    #pragma unroll
    for (int j = 0; j < 4; ++j) acc[i][j] = zero4;

  for (int k0 = 0; k0 < K; k0 += 32) {
    const int4 a0 = *(const int4*)(A + (size_t)(row0 + lrow) * K + k0 + lcol);
    const int4 a1 = *(const int4*)(A + (size_t)(row0 + lrow + 64) * K + k0 + lcol);
    const int4 b0 = *(const int4*)(Bt + (size_t)(col0 + lrow) * K + k0 + lcol);
    const int4 b1 = *(const int4*)(Bt + (size_t)(col0 + lrow + 64) * K + k0 + lcol);
    __syncthreads();
    *(int4*)&As[lrow * 32 + lcol] = a0;
    *(int4*)&As[(lrow + 64) * 32 + lcol] = a1;
    *(int4*)&Bs[lrow * 32 + lcol] = b0;
    *(int4*)&Bs[(lrow + 64) * 32 + lcol] = b1;
    __syncthreads();
    bf16x8 af[4], bfr[4];
    #pragma unroll
    for (int i = 0; i < 4; ++i)
      af[i] = *(const bf16x8*)&As[(wm + i * 16 + fr) * 32 + kh * 8];
    #pragma unroll
    for (int j = 0; j < 4; ++j)
      bfr[j] = *(const bf16x8*)&Bs[(wn + j * 16 + fr) * 32 + kh * 8];
    #pragma unroll
    for (int i = 0; i < 4; ++i)
      #pragma unroll
      for (int j = 0; j < 4; ++j)
        acc[i][j] = MFMA16(af[i], bfr[j], acc[i][j]);
  }

  #pragma unroll
  for (int i = 0; i < 4; ++i) {
    #pragma unroll
    for (int j = 0; j < 4; ++j) {
      #pragma unroll
      for (int r = 0; r < 4; ++r) {
        int row = row0 + wm + i * 16 + kh * 4 + r;
        int col = col0 + wn + j * 16 + fr;
        float bb = bias[col];
        if (EPI == 0 && col < 256) bb *= 0.17677669529663687f;
        float v = acc[i][j][r] + bb;
        if (EPI == 0) {
          int part = col >> 8, head = (col >> 5) & 7, hd = col & 31;
          int widx = row / 98, n = row - widx * 98;
          size_t off = ((size_t)(part * 512 + widx) * 8 + head) * 3136 + (size_t)n * 32 + hd;
          out_bf[off] = __float2bfloat16(v);
        } else if (EPI == 1) {
          int widx = row / 98, n = row - widx * 98;
          int zd = widx >> 6, zh = (widx >> 3) & 7, zw = widx & 7;
          int ld = n / 49, rem = n - ld * 49, lh = rem / 7, lw = rem - lh * 7;
          int d = zd * 2 + ld, h = zh * 7 + lh, w = zw * 7 + lw;
          int dsrc = (d + 1) & 15;
          int hsrc = h + 3; if (hsrc >= 56) hsrc -= 56;
          int wsrc = w + 3; if (wsrc >= 56) wsrc -= 56;
          size_t tok = (size_t)(dsrc * 56 + hsrc) * 56 + wsrc;
          out_f[tok * 256 + col] = add_f[tok * 256 + col] + v;
        } else if (EPI == 2) {
          float gl = 0.5f * v * (1.0f + erff(v * 0.70710678118654752f));
          out_bf[(size_t)row * 1024 + col] = __float2bfloat16(gl);
        } else {
          size_t ro = (size_t)(mrow0 + row);
          out_f[ro * 256 + col] = add_f[ro * 256 + col] + v;
        }
      }
    }
  }
}

// ---------------- windowed attention: one block per (window, head)
__global__ __launch_bounds__(256) void attn_k(const bf16* __restrict__ qkv,
                                              const float* __restrict__ biasT,
                                              const float* __restrict__ maskM,
                                              bf16* __restrict__ out) {
  __shared__ bf16 Qs[128 * 32];
  __shared__ bf16 Ks[112 * 32];
  __shared__ bf16 Vt[32 * 128];            // Vt[c][r], XOR-swizzled
  __shared__ unsigned short Pl[112 * 128]; // P[row][m], XOR-swizzled
  const int tid = threadIdx.x;
  const int widx = blockIdx.x >> 3, head = blockIdx.x & 7;
  const bf16* qb = qkv + ((size_t)widx * 8 + head) * 3136;
  const bf16* kb = qb + (size_t)12845056;
  const bf16* vb = qb + (size_t)2 * 12845056;
  const unsigned short* qbu = (const unsigned short*)qb;
  const unsigned short* kbu = (const unsigned short*)kb;
  const unsigned short* vbu = (const unsigned short*)vb;
  ushort4 z4; z4.x = z4.y = z4.z = z4.w = 0;

  for (int i = tid; i < 1024; i += 256) {           // Q: 128 rows x 32 (pad 0)
    int row = i >> 3;
    ushort4 val = (row < 98) ? *(const ushort4*)(qbu + i * 4) : z4;
    *(ushort4*)((unsigned short*)Qs + i * 4) = val;
  }
  for (int i = tid; i < 896; i += 256) {            // K: 112 rows x 32 (pad 0)
    int row = i >> 3;
    ushort4 val = (row < 98) ? *(const ushort4*)(kbu + i * 4) : z4;
    *(ushort4*)((unsigned short*)Ks + i * 4) = val;
  }
  for (int i = tid; i < 4096; i += 256) {           // Vt[c][r] transposed, swizzled
    int r = i & 127, c = i >> 7;
    unsigned short val = (r < 98) ? vbu[r * 32 + c] : (unsigned short)0;
    ((unsigned short*)Vt)[i ^ ((c & 7) << 3)] = val;
  }
  __syncthreads();

  const int wid = tid >> 6, lane = tid & 63;
  const int fr = lane & 15, kh = lane >> 4;
  const int ntr = (wid < 3) ? 2 : 1;
  const int tr0 = wid * 2;

  f32x4 zero4 = {0.f, 0.f, 0.f, 0.f};
  f32x4 s[2][7];
  #pragma unroll
  for (int a = 0; a < 2; ++a)
    #pragma unroll
    for (int m = 0; m < 7; ++m) s[a][m] = zero4;

  bf16x8 aq[2];
  for (int ti = 0; ti < ntr; ++ti)
    aq[ti] = *(const bf16x8*)&Qs[((tr0 + ti) * 16 + fr) * 32 + kh * 8];
  for (int mt = 0; mt < 7; ++mt) {
    bf16x8 bk = *(const bf16x8*)&Ks[(mt * 16 + fr) * 32 + kh * 8];
    for (int ti = 0; ti < ntr; ++ti)
      s[ti][mt] = MFMA16(aq[ti], bk, s[ti][mt]);
  }

  // wave-local softmax: row lives in an aligned 16-lane group (same l>>4)
  for (int ti = 0; ti < ntr; ++ti) {
    int tr = tr0 + ti;
    #pragma unroll
    for (int r = 0; r < 4; ++r) {
      int row = tr * 16 + kh * 4 + r;
      bool rv = row < 98;
      float vals[7];
      float mx = -1e30f;
      #pragma unroll
      for (int mt = 0; mt < 7; ++mt) {
        int m = mt * 16 + fr;
        float sv = -1e30f;
        if (rv && m < 98)
          sv = s[ti][mt][r] + biasT[head * 9604 + row * 98 + m]
                            + maskM[(size_t)widx * 9604 + row * 98 + m];
        vals[mt] = sv;
        mx = fmaxf(mx, sv);
      }
      #pragma unroll
      for (int d = 1; d < 16; d <<= 1) mx = fmaxf(mx, __shfl_xor(mx, d));
      float sum = 0.f;
      float p[7];
      #pragma unroll
      for (int mt = 0; mt < 7; ++mt) {
        float e = (vals[mt] > -1e29f) ? __expf(vals[mt] - mx) : 0.f;
        p[mt] = e; sum += e;
      }
      #pragma unroll
      for (int d = 1; d < 16; d <<= 1) sum += __shfl_xor(sum, d);
      float inv = rv ? (1.0f / sum) : 0.f;
      #pragma unroll
      for (int mt = 0; mt < 7; ++mt) {
        int m = mt * 16 + fr;
        Pl[(row * 128 + m) ^ ((row & 7) << 3)] = bfbits(p[mt] * inv);
      }
      Pl[(row * 128 + 112 + fr) ^ ((row & 7) << 3)] = 0;  // zero tail cols
    }
  }
  __syncthreads();

  // PV: out[row][c] = sum_m P[row][m] * V[m][c]
  f32x4 o[2][2];
  #pragma unroll
  for (int a = 0; a < 2; ++a)
    #pragma unroll
    for (int c = 0; c < 2; ++c) o[a][c] = zero4;

  for (int ti = 0; ti < ntr; ++ti) {
    int tr = tr0 + ti;
    int prow = tr * 16 + fr;
    #pragma unroll
    for (int kk = 0; kk < 4; ++kk) {
      bf16x8 pa = *(const bf16x8*)&((const bf16*)Pl)[(prow * 128 + kk * 32 + kh * 8) ^ ((prow & 7) << 3)];
      #pragma unroll
      for (int ct = 0; ct < 2; ++ct) {
        int vrow = ct * 16 + fr;
        bf16x8 vv = *(const bf16x8*)&Vt[(vrow * 128 + kk * 32 + kh * 8) ^ ((vrow & 7) << 3)];
        o[ti][ct] = MFMA16(pa, vv, o[ti][ct]);
      }
    }
  }
  for (int ti = 0; ti < ntr; ++ti) {
    int tr = tr0 + ti;
    #pragma unroll
    for (int ct = 0; ct < 2; ++ct) {
      #pragma unroll
      for (int r = 0; r < 4; ++r) {
        int row = tr * 16 + kh * 4 + r;
        if (row < 98) {
          size_t grow = (size_t)widx * 98 + row;
          int col = head * 32 + ct * 16 + fr;
          out[grow * 256 + col] = __float2bfloat16(o[ti][ct][r]);
        }
      }
    }
  }
}

extern "C" void kernel_launch(void* const* d_in, const int* in_sizes, int n_in,
                              void* d_out, int out_size, void* d_ws, size_t ws_size,
                              hipStream_t stream) {
  const float* x      = (const float*)d_in[0];
  const float* maskM  = (const float*)d_in[1];
  const float* g1     = (const float*)d_in[2];
  const float* b1     = (const float*)d_in[3];
  const float* qkv_w  = (const float*)d_in[4];
  const float* qkv_b  = (const float*)d_in[5];
  const float* rpb    = (const float*)d_in[6];
  const float* proj_w = (const float*)d_in[7];
  const float* proj_b = (const float*)d_in[8];
  const float* g2     = (const float*)d_in[9];
  const float* b2     = (const float*)d_in[10];
  const float* fc1_w  = (const float*)d_in[11];
  const float* fc1_b  = (const float*)d_in[12];
  const float* fc2_w  = (const float*)d_in[13];
  const float* fc2_b  = (const float*)d_in[14];
  float* outp = (float*)d_out;

  char* ws = (char*)d_ws;
  if (ws_size < (size_t)156237824) return;  // need ~149 MB scratch
  bf16*  wqkvT  = (bf16*)(ws + 0);          // 768x256
  bf16*  wprojT = (bf16*)(ws + 393216);     // 256x256
  bf16*  wfc1T  = (bf16*)(ws + 524288);     // 1024x256
  bf16*  wfc2T  = (bf16*)(ws + 1048576);    // 256x1024
  float* biasT  = (float*)(ws + 1572864);   // 8x98x98
  float* x2     = (float*)(ws + 2097152);   // 50176x256 f32
  char*  pool   = ws + 53477376;
  bf16*  xw       = (bf16*)pool;                    // 50176x256 bf16
  bf16*  qkvb     = (bf16*)(pool + 25690112);       // 3x512x8x98x32 bf16
  bf16*  attn_out = (bf16*)pool;                    // reuses xw
  bf16*  hbuf     = (bf16*)pool;                    // reuses attn_out
  bf16*  hh       = (bf16*)(pool + 25690112);       // 25088x1024 bf16 (chunk), reuses qkvb

  transpose_w<<<768, 256, 0, stream>>>(qkv_w, wqkvT, 768, 256, 256, 0.17677669529663687f);
  transpose_w<<<256, 256, 0, stream>>>(proj_w, wprojT, 256, 256, 0, 1.f);
  transpose_w<<<1024, 256, 0, stream>>>(fc1_w, wfc1T, 1024, 256, 0, 1.f);
  transpose_w<<<1024, 256, 0, stream>>>(fc2_w, wfc2T, 256, 1024, 0, 1.f);
  bias_table<<<38, 256, 0, stream>>>(rpb, biasT);

  ln_k<<<12544, 256, 0, stream>>>(x, g1, b1, xw, 1);
  gemm_k<0><<<dim3(392, 6), 256, 0, stream>>>(xw, wqkvT, qkv_b, 768, 256, 0, qkvb, nullptr, nullptr);
  attn_k<<<4096, 256, 0, stream>>>(qkvb, biasT, maskM, attn_out);
  gemm_k<1><<<dim3(392, 2), 256, 0, stream>>>(attn_out, wprojT, proj_b, 256, 256, 0, nullptr, x2, x);
  ln_k<<<12544, 256, 0, stream>>>(x2, g2, b2, hbuf, 0);
  for (int ch = 0; ch < 2; ++ch) {
    gemm_k<2><<<dim3(196, 8), 256, 0, stream>>>(hbuf + (size_t)ch * 25088 * 256, wfc1T, fc1_b,
                                                1024, 256, 0, hh, nullptr, nullptr);
    gemm_k<3><<<dim3(196, 2), 256, 0, stream>>>(hh, wfc2T, fc2_b, 256, 1024, ch * 25088,
                                                nullptr, outp, x2);
  }
}

// Round 2
// 657.817 us; speedup vs baseline: 1.0450x; 1.0450x over previous
//
#include <hip/hip_runtime.h>
#include <hip/hip_bf16.h>

typedef __hip_bfloat16 bf16;
typedef __attribute__((ext_vector_type(4))) float f32x4;
typedef __attribute__((ext_vector_type(8))) short bf16x8;

#define MFMA16(a,b,c) __builtin_amdgcn_mfma_f32_16x16x32_bf16((a),(b),(c),0,0,0)

static __device__ inline unsigned short bfbits(float f) {
  __hip_bfloat16 h = __float2bfloat16(f);
  union { __hip_bfloat16 h; unsigned short u; } u;
  u.h = h; return u.u;
}
static __device__ inline float bf2f(unsigned short u) {
  return __uint_as_float(((unsigned int)u) << 16);
}
static __device__ inline void gld16(const void* g, void* l) {
  __builtin_amdgcn_global_load_lds((const __attribute__((address_space(1))) void*)g,
                                   (__attribute__((address_space(3))) void*)l, 16, 0, 0);
}

// ---------------- weight transpose + bf16 (+ optional q-scale on first scaleN cols)
__global__ __launch_bounds__(256) void transpose_w(const float* __restrict__ src,
                                                   bf16* __restrict__ dst,
                                                   int N, int K, int scaleN, float scale) {
  int idx = blockIdx.x * 256 + threadIdx.x;
  if (idx >= N * K) return;
  int n = idx / K, k = idx - n * K;
  float v = src[(size_t)k * N + n];
  if (n < scaleN) v *= scale;
  dst[idx] = __float2bfloat16(v);
}

// ---------------- relative position bias table (bf16): biasT[h][n][m]
__global__ __launch_bounds__(256) void bias_table_bf(const float* __restrict__ rpb,
                                                     unsigned short* __restrict__ biasT) {
  int idx = blockIdx.x * 256 + threadIdx.x;
  if (idx >= 98 * 98) return;
  int nn = idx / 98, mm = idx - nn * 98;
  int ld = nn / 49, lrem = nn - ld * 49, lh = lrem / 7, lw = lrem - lh * 7;
  int md = mm / 49, mrem = mm - md * 49, mh = mrem / 7, mw = mrem - mh * 7;
  int rel = (ld - md + 1) * 169 + (lh - mh + 6) * 13 + (lw - mw + 6);
  #pragma unroll
  for (int h = 0; h < 8; ++h)
    biasT[h * 9604 + idx] = bfbits(rpb[rel * 8 + h]);
}

// ---------------- f32 -> bf16 bulk convert (mask table)
__global__ __launch_bounds__(256) void f2bf_k(const float* __restrict__ src,
                                              unsigned short* __restrict__ dst, int n) {
  int i = blockIdx.x * 256 + threadIdx.x;
  if (i < n) dst[i] = bfbits(src[i]);
}

// ---------------- LayerNorm (one wave per token, 4 ch/lane).
// windowed=1: output rows are window-ordered (LN1 + roll + partition fused)
__global__ __launch_bounds__(256) void ln_k(const float* __restrict__ x,
                                            const float* __restrict__ g,
                                            const float* __restrict__ bias,
                                            bf16* __restrict__ out, int windowed) {
  const int wid = threadIdx.x >> 6, lane = threadIdx.x & 63;
  const int t = blockIdx.x * 4 + wid;   // destination row
  int src = t;
  if (windowed) {
    int widx = t / 98, n = t - widx * 98;
    int zd = widx >> 6, zh = (widx >> 3) & 7, zw = widx & 7;
    int ld = n / 49, rem = n - ld * 49, lh = rem / 7, lw = rem - lh * 7;
    int d = zd * 2 + ld, h = zh * 7 + lh, w = zw * 7 + lw;
    int dsrc = (d + 1) & 15;
    int hsrc = h + 3; if (hsrc >= 56) hsrc -= 56;
    int wsrc = w + 3; if (wsrc >= 56) wsrc -= 56;
    src = (dsrc * 56 + hsrc) * 56 + wsrc;
  }
  const float4 v = *(const float4*)(x + (size_t)src * 256 + lane * 4);
  float s1 = v.x + v.y + v.z + v.w;
  float s2 = v.x * v.x + v.y * v.y + v.z * v.z + v.w * v.w;
  #pragma unroll
  for (int d = 1; d < 64; d <<= 1) {
    s1 += __shfl_xor(s1, d);
    s2 += __shfl_xor(s2, d);
  }
  float mu = s1 * (1.f / 256.f);
  float var = s2 * (1.f / 256.f) - mu * mu;
  float rs = rsqrtf(var + 1e-5f);
  const float4 gv = *(const float4*)(g + lane * 4);
  const float4 bv = *(const float4*)(bias + lane * 4);
  ushort4 pk;
  pk.x = bfbits((v.x - mu) * rs * gv.x + bv.x);
  pk.y = bfbits((v.y - mu) * rs * gv.y + bv.y);
  pk.z = bfbits((v.z - mu) * rs * gv.z + bv.z);
  pk.w = bfbits((v.w - mu) * rs * gv.w + bv.w);
  *(ushort4*)((unsigned short*)out + (size_t)t * 256 + lane * 4) = pk;
}

// ---------------- GEMM: C = A[M x K]bf16 @ Bt[N x K]bf16^T + bias, fused epilogues
// EPI 0: scatter to qkv[3][512][8][98][32] (q-scale folded into Bt & bias here)
// EPI 1: proj -> window-reverse+unroll residual add with x -> x2 (fp32)
// EPI 2: exact GELU -> bf16 row-major stride 1024
// EPI 3: + x2 residual -> fp32 out row-major stride 256 (rows offset by mrow0)
template<int EPI>
__global__ __launch_bounds__(256) void gemm_k(const bf16* __restrict__ A,
                                              const bf16* __restrict__ Bt,
                                              const float* __restrict__ bias,
                                              int N, int K, int mrow0,
                                              bf16* __restrict__ out_bf,
                                              float* __restrict__ out_f,
                                              const float* __restrict__ add_f) {
  __shared__ bf16 As[128 * 32];
  __shared__ bf16 Bs[128 * 32];
  const int tid = threadIdx.x;
  const int wid = tid >> 6, lane = tid & 63;
  const int row0 = blockIdx.x * 128, col0 = blockIdx.y * 128;
  const int lrow = tid >> 2, lcol = (tid & 3) * 8;
  const int fr = lane & 15, kh = lane >> 4;
  const int wm = (wid >> 1) * 64, wn = (wid & 1) * 64;
  f32x4 zero4 = {0.f, 0.f, 0.f, 0.f};
  f32x4 acc[4][4];
  #pragma unroll
  for (int i = 0; i < 4; ++i)
    #pragma unroll
    for (int j = 0; j < 4; ++j) acc[i][j] = zero4;

  const bf16* aP = A + (size_t)(row0 + lrow) * K + lcol;
  const bf16* bP = Bt + (size_t)(col0 + lrow) * K + lcol;
  bf16* asD = &As[lrow * 32 + lcol];
  bf16* bsD = &Bs[lrow * 32 + lcol];

  for (int k0 = 0; k0 < K; k0 += 32) {
    __syncthreads();                       // LDS consumers of prev iter done
    gld16(aP + k0, asD);
    gld16(aP + (size_t)64 * K + k0, asD + 64 * 32);
    gld16(bP + k0, bsD);
    gld16(bP + (size_t)64 * K + k0, bsD + 64 * 32);
    __syncthreads();                       // vmcnt(0) drained by barrier
    bf16x8 af[4], bfr[4];
    #pragma unroll
    for (int i = 0; i < 4; ++i)
      af[i] = *(const bf16x8*)&As[(wm + i * 16 + fr) * 32 + kh * 8];
    #pragma unroll
    for (int j = 0; j < 4; ++j)
      bfr[j] = *(const bf16x8*)&Bs[(wn + j * 16 + fr) * 32 + kh * 8];
    #pragma unroll
    for (int i = 0; i < 4; ++i)
      #pragma unroll
      for (int j = 0; j < 4; ++j)
        acc[i][j] = MFMA16(af[i], bfr[j], acc[i][j]);
  }

  #pragma unroll
  for (int i = 0; i < 4; ++i) {
    #pragma unroll
    for (int j = 0; j < 4; ++j) {
      #pragma unroll
      for (int r = 0; r < 4; ++r) {
        int row = row0 + wm + i * 16 + kh * 4 + r;
        int col = col0 + wn + j * 16 + fr;
        float bb = bias[col];
        if (EPI == 0 && col < 256) bb *= 0.17677669529663687f;
        float v = acc[i][j][r] + bb;
        if (EPI == 0) {
          int part = col >> 8, head = (col >> 5) & 7, hd = col & 31;
          int widx = row / 98, n = row - widx * 98;
          size_t off = ((size_t)(part * 512 + widx) * 8 + head) * 3136 + (size_t)n * 32 + hd;
          out_bf[off] = __float2bfloat16(v);
        } else if (EPI == 1) {
          int widx = row / 98, n = row - widx * 98;
          int zd = widx >> 6, zh = (widx >> 3) & 7, zw = widx & 7;
          int ld = n / 49, rem = n - ld * 49, lh = rem / 7, lw = rem - lh * 7;
          int d = zd * 2 + ld, h = zh * 7 + lh, w = zw * 7 + lw;
          int dsrc = (d + 1) & 15;
          int hsrc = h + 3; if (hsrc >= 56) hsrc -= 56;
          int wsrc = w + 3; if (wsrc >= 56) wsrc -= 56;
          size_t tok = (size_t)(dsrc * 56 + hsrc) * 56 + wsrc;
          out_f[tok * 256 + col] = add_f[tok * 256 + col] + v;
        } else if (EPI == 2) {
          float gl = 0.5f * v * (1.0f + erff(v * 0.70710678118654752f));
          out_bf[(size_t)row * 1024 + col] = __float2bfloat16(gl);
        } else {
          size_t ro = (size_t)(mrow0 + row);
          out_f[ro * 256 + col] = add_f[ro * 256 + col] + v;
        }
      }
    }
  }
}

// ---------------- windowed attention: one block per WINDOW, loops all 8 heads
__global__ __launch_bounds__(256) void attn_k(const bf16* __restrict__ qkv,
                                              const unsigned short* __restrict__ bias_bf,
                                              const unsigned short* __restrict__ mask_bf,
                                              bf16* __restrict__ out) {
  __shared__ bf16 Qs[112 * 32];
  __shared__ bf16 Ks[112 * 32];
  __shared__ bf16 Vt[32 * 128];            // Vt[c][r], XOR-swizzled
  __shared__ unsigned short Pl[112 * 128]; // P[row][m], XOR-swizzled
  __shared__ unsigned short bmS[98 * 100]; // bias+mask bf16, stride 100
  const int tid = threadIdx.x;
  const int widx = blockIdx.x;
  const int wid = tid >> 6, lane = tid & 63;
  const int fr = lane & 15, kh = lane >> 4;
  const int ntr = (wid < 3) ? 2 : 1;
  const int tr0 = wid * 2;
  const unsigned short* mrow = mask_bf + (size_t)widx * 9604;
  ushort4 z4; z4.x = z4.y = z4.z = z4.w = 0;
  f32x4 zero4 = {0.f, 0.f, 0.f, 0.f};

  for (int head = 0; head < 8; ++head) {
    const bf16* qb = qkv + ((size_t)widx * 8 + head) * 3136;
    const unsigned short* qbu = (const unsigned short*)qb;
    const unsigned short* kbu = qbu + (size_t)12845056;
    const unsigned short* vbu = qbu + (size_t)2 * 12845056;
    const unsigned short* brow = bias_bf + head * 9604;

    __syncthreads();                       // prev head's LDS readers done
    for (int i = tid; i < 896; i += 256) { // Q,K: 112 rows x 32 (pad 0)
      int row = i >> 3;
      ushort4 qv = (row < 98) ? *(const ushort4*)(qbu + i * 4) : z4;
      *(ushort4*)((unsigned short*)Qs + i * 4) = qv;
      ushort4 kv = (row < 98) ? *(const ushort4*)(kbu + i * 4) : z4;
      *(ushort4*)((unsigned short*)Ks + i * 4) = kv;
    }
    for (int i = tid; i < 4096; i += 256) { // Vt[c][r] transposed, swizzled
      int r = i & 127, c = i >> 7;
      unsigned short val = (r < 98) ? vbu[r * 32 + c] : (unsigned short)0;
      ((unsigned short*)Vt)[i ^ ((c & 7) << 3)] = val;
    }
    for (int j = tid; j < 4802; j += 256) { // bias+mask -> bmS (2 elems/iter)
      int n = j / 49, m2 = (j - n * 49) * 2;
      int src = n * 98 + m2;
      unsigned int bb = *(const unsigned int*)(brow + src);
      unsigned int mm = *(const unsigned int*)(mrow + src);
      float f0 = __uint_as_float(bb << 16) + __uint_as_float(mm << 16);
      float f1 = __uint_as_float(bb & 0xffff0000u) + __uint_as_float(mm & 0xffff0000u);
      unsigned int pk = (unsigned int)bfbits(f0) | ((unsigned int)bfbits(f1) << 16);
      *(unsigned int*)&bmS[n * 100 + m2] = pk;
    }
    __syncthreads();

    // QK^T
    f32x4 s[2][7];
    #pragma unroll
    for (int a = 0; a < 2; ++a)
      #pragma unroll
      for (int m = 0; m < 7; ++m) s[a][m] = zero4;
    bf16x8 aq[2];
    for (int ti = 0; ti < ntr; ++ti)
      aq[ti] = *(const bf16x8*)&Qs[((tr0 + ti) * 16 + fr) * 32 + kh * 8];
    for (int mt = 0; mt < 7; ++mt) {
      bf16x8 bk = *(const bf16x8*)&Ks[(mt * 16 + fr) * 32 + kh * 8];
      for (int ti = 0; ti < ntr; ++ti)
        s[ti][mt] = MFMA16(aq[ti], bk, s[ti][mt]);
    }

    // softmax (row lives in an aligned 16-lane group), bias+mask from LDS
    for (int ti = 0; ti < ntr; ++ti) {
      int tr = tr0 + ti;
      #pragma unroll
      for (int r = 0; r < 4; ++r) {
        int row = tr * 16 + kh * 4 + r;
        bool rv = row < 98;
        float vals[7];
        float mx = -1e30f;
        #pragma unroll
        for (int mt = 0; mt < 7; ++mt) {
          int m = mt * 16 + fr;
          float sv = -1e30f;
          if (rv && m < 98)
            sv = s[ti][mt][r] + bf2f(bmS[row * 100 + m]);
          vals[mt] = sv;
          mx = fmaxf(mx, sv);
        }
        #pragma unroll
        for (int d = 1; d < 16; d <<= 1) mx = fmaxf(mx, __shfl_xor(mx, d));
        float sum = 0.f;
        float p[7];
        #pragma unroll
        for (int mt = 0; mt < 7; ++mt) {
          float e = (vals[mt] > -1e29f) ? __expf(vals[mt] - mx) : 0.f;
          p[mt] = e; sum += e;
        }
        #pragma unroll
        for (int d = 1; d < 16; d <<= 1) sum += __shfl_xor(sum, d);
        float inv = rv ? (1.0f / sum) : 0.f;
        #pragma unroll
        for (int mt = 0; mt < 7; ++mt) {
          int m = mt * 16 + fr;
          Pl[(row * 128 + m) ^ ((row & 7) << 3)] = bfbits(p[mt] * inv);
        }
        Pl[(row * 128 + 112 + fr) ^ ((row & 7) << 3)] = 0;  // zero tail cols
      }
    }
    __syncthreads();

    // PV: out[row][c] = sum_m P[row][m] * V[m][c]
    f32x4 o[2][2];
    #pragma unroll
    for (int a = 0; a < 2; ++a)
      #pragma unroll
      for (int c = 0; c < 2; ++c) o[a][c] = zero4;
    for (int ti = 0; ti < ntr; ++ti) {
      int tr = tr0 + ti;
      int prow = tr * 16 + fr;
      #pragma unroll
      for (int kk = 0; kk < 4; ++kk) {
        bf16x8 pa = *(const bf16x8*)&((const bf16*)Pl)[(prow * 128 + kk * 32 + kh * 8) ^ ((prow & 7) << 3)];
        #pragma unroll
        for (int ct = 0; ct < 2; ++ct) {
          int vrow = ct * 16 + fr;
          bf16x8 vv = *(const bf16x8*)&Vt[(vrow * 128 + kk * 32 + kh * 8) ^ ((vrow & 7) << 3)];
          o[ti][ct] = MFMA16(pa, vv, o[ti][ct]);
        }
      }
    }
    for (int ti = 0; ti < ntr; ++ti) {
      int tr = tr0 + ti;
      #pragma unroll
      for (int ct = 0; ct < 2; ++ct) {
        #pragma unroll
        for (int r = 0; r < 4; ++r) {
          int row = tr * 16 + kh * 4 + r;
          if (row < 98) {
            size_t grow = (size_t)widx * 98 + row;
            int col = head * 32 + ct * 16 + fr;
            out[grow * 256 + col] = __float2bfloat16(o[ti][ct][r]);
          }
        }
      }
    }
  }
}

extern "C" void kernel_launch(void* const* d_in, const int* in_sizes, int n_in,
                              void* d_out, int out_size, void* d_ws, size_t ws_size,
                              hipStream_t stream) {
  const float* x      = (const float*)d_in[0];
  const float* maskM  = (const float*)d_in[1];
  const float* g1     = (const float*)d_in[2];
  const float* b1     = (const float*)d_in[3];
  const float* qkv_w  = (const float*)d_in[4];
  const float* qkv_b  = (const float*)d_in[5];
  const float* rpb    = (const float*)d_in[6];
  const float* proj_w = (const float*)d_in[7];
  const float* proj_b = (const float*)d_in[8];
  const float* g2     = (const float*)d_in[9];
  const float* b2     = (const float*)d_in[10];
  const float* fc1_w  = (const float*)d_in[11];
  const float* fc1_b  = (const float*)d_in[12];
  const float* fc2_w  = (const float*)d_in[13];
  const float* fc2_b  = (const float*)d_in[14];
  float* outp = (float*)d_out;

  char* ws = (char*)d_ws;
  if (ws_size < (size_t)156237824) return;  // need ~149 MB scratch
  bf16*  wqkvT   = (bf16*)(ws + 0);          // 768x256
  bf16*  wprojT  = (bf16*)(ws + 393216);     // 256x256
  bf16*  wfc1T   = (bf16*)(ws + 524288);     // 1024x256
  bf16*  wfc2T   = (bf16*)(ws + 1048576);    // 256x1024
  unsigned short* bias_bf = (unsigned short*)(ws + 1572864);  // 8x9604 bf16
  float* x2      = (float*)(ws + 2097152);   // 50176x256 f32 (written after attn)
  unsigned short* mask_bf = (unsigned short*)(ws + 2097152);  // 512x9604 bf16, aliases x2 (dead until gemm<1>)
  char*  pool    = ws + 53477376;
  bf16*  xw       = (bf16*)pool;                    // 50176x256 bf16
  bf16*  qkvb     = (bf16*)(pool + 25690112);       // 3x512x8x98x32 bf16
  bf16*  attn_out = (bf16*)pool;                    // reuses xw
  bf16*  hbuf     = (bf16*)pool;                    // reuses attn_out
  bf16*  hh       = (bf16*)(pool + 25690112);       // 25088x1024 bf16 (chunk), reuses qkvb

  transpose_w<<<768, 256, 0, stream>>>(qkv_w, wqkvT, 768, 256, 256, 0.17677669529663687f);
  transpose_w<<<256, 256, 0, stream>>>(proj_w, wprojT, 256, 256, 0, 1.f);
  transpose_w<<<1024, 256, 0, stream>>>(fc1_w, wfc1T, 1024, 256, 0, 1.f);
  transpose_w<<<1024, 256, 0, stream>>>(fc2_w, wfc2T, 256, 1024, 0, 1.f);
  bias_table_bf<<<38, 256, 0, stream>>>(rpb, bias_bf);
  f2bf_k<<<19208, 256, 0, stream>>>(maskM, mask_bf, 512 * 9604);

  ln_k<<<12544, 256, 0, stream>>>(x, g1, b1, xw, 1);
  gemm_k<0><<<dim3(392, 6), 256, 0, stream>>>(xw, wqkvT, qkv_b, 768, 256, 0, qkvb, nullptr, nullptr);
  attn_k<<<512, 256, 0, stream>>>(qkvb, bias_bf, mask_bf, attn_out);
  gemm_k<1><<<dim3(392, 2), 256, 0, stream>>>(attn_out, wprojT, proj_b, 256, 256, 0, nullptr, x2, x);
  ln_k<<<12544, 256, 0, stream>>>(x2, g2, b2, hbuf, 0);
  for (int ch = 0; ch < 2; ++ch) {
    gemm_k<2><<<dim3(196, 8), 256, 0, stream>>>(hbuf + (size_t)ch * 25088 * 256, wfc1T, fc1_b,
                                                1024, 256, 0, hh, nullptr, nullptr);
    gemm_k<3><<<dim3(196, 2), 256, 0, stream>>>(hh, wfc2T, fc2_b, 256, 1024, ch * 25088,
                                                nullptr, outp, x2);
  }
}

// Round 3
// 435.873 us; speedup vs baseline: 1.5771x; 1.5092x over previous
//
#include <hip/hip_runtime.h>
#include <hip/hip_bf16.h>

typedef __hip_bfloat16 bf16;
typedef __attribute__((ext_vector_type(4))) float f32x4;
typedef __attribute__((ext_vector_type(8))) short bf16x8;

#define MFMA16(a,b,c) __builtin_amdgcn_mfma_f32_16x16x32_bf16((a),(b),(c),0,0,0)

static __device__ inline unsigned short bfbits(float f) {
  __hip_bfloat16 h = __float2bfloat16(f);
  union { __hip_bfloat16 h; unsigned short u; } u;
  u.h = h; return u.u;
}
static __device__ inline float bf2f(unsigned short u) {
  return __uint_as_float(((unsigned int)u) << 16);
}
static __device__ inline void gld16(const void* g, void* l) {
  __builtin_amdgcn_global_load_lds((const __attribute__((address_space(1))) void*)g,
                                   (__attribute__((address_space(3))) void*)l, 16, 0, 0);
}

// ---------------- weight transpose + bf16 (+ optional q-scale on first scaleN cols)
__global__ __launch_bounds__(256) void transpose_w(const float* __restrict__ src,
                                                   bf16* __restrict__ dst,
                                                   int N, int K, int scaleN, float scale) {
  int idx = blockIdx.x * 256 + threadIdx.x;
  if (idx >= N * K) return;
  int n = idx / K, k = idx - n * K;
  float v = src[(size_t)k * N + n];
  if (n < scaleN) v *= scale;
  dst[idx] = __float2bfloat16(v);
}

// ---------------- relative position bias table (bf16): biasT[h][n][m]
__global__ __launch_bounds__(256) void bias_table_bf(const float* __restrict__ rpb,
                                                     unsigned short* __restrict__ biasT) {
  int idx = blockIdx.x * 256 + threadIdx.x;
  if (idx >= 98 * 98) return;
  int nn = idx / 98, mm = idx - nn * 98;
  int ld = nn / 49, lrem = nn - ld * 49, lh = lrem / 7, lw = lrem - lh * 7;
  int md = mm / 49, mrem = mm - md * 49, mh = mrem / 7, mw = mrem - mh * 7;
  int rel = (ld - md + 1) * 169 + (lh - mh + 6) * 13 + (lw - mw + 6);
  #pragma unroll
  for (int h = 0; h < 8; ++h)
    biasT[h * 9604 + idx] = bfbits(rpb[rel * 8 + h]);
}

// ---------------- f32 -> bf16 bulk convert (mask table)
__global__ __launch_bounds__(256) void f2bf_k(const float* __restrict__ src,
                                              unsigned short* __restrict__ dst, int n) {
  int i = blockIdx.x * 256 + threadIdx.x;
  if (i < n) dst[i] = bfbits(src[i]);
}

// ---------------- V transpose: qkv V part [wh][98][32] -> vt [wh][32][128] (pad 0)
__global__ __launch_bounds__(256) void vtrans_k(const unsigned short* __restrict__ v,
                                                unsigned short* __restrict__ vt) {
  __shared__ unsigned short S[98 * 33];
  const unsigned short* src = v + (size_t)blockIdx.x * 3136;
  for (int i = threadIdx.x; i < 3136; i += 256) {
    int n = i >> 5, d = i & 31;
    S[n * 33 + d] = src[i];
  }
  __syncthreads();
  unsigned short* dst = vt + ((size_t)blockIdx.x << 12);
  for (int i = threadIdx.x; i < 4096; i += 256) {
    int d = i >> 7, m = i & 127;
    dst[i] = (m < 98) ? S[m * 33 + d] : (unsigned short)0;
  }
}

// ---------------- LayerNorm (one wave per token, 4 ch/lane).
// windowed=1: output rows are window-ordered (LN1 + roll + partition fused)
__global__ __launch_bounds__(256) void ln_k(const float* __restrict__ x,
                                            const float* __restrict__ g,
                                            const float* __restrict__ bias,
                                            bf16* __restrict__ out, int windowed) {
  const int wid = threadIdx.x >> 6, lane = threadIdx.x & 63;
  const int t = blockIdx.x * 4 + wid;   // destination row
  int src = t;
  if (windowed) {
    int widx = t / 98, n = t - widx * 98;
    int zd = widx >> 6, zh = (widx >> 3) & 7, zw = widx & 7;
    int ld = n / 49, rem = n - ld * 49, lh = rem / 7, lw = rem - lh * 7;
    int d = zd * 2 + ld, h = zh * 7 + lh, w = zw * 7 + lw;
    int dsrc = (d + 1) & 15;
    int hsrc = h + 3; if (hsrc >= 56) hsrc -= 56;
    int wsrc = w + 3; if (wsrc >= 56) wsrc -= 56;
    src = (dsrc * 56 + hsrc) * 56 + wsrc;
  }
  const float4 v = *(const float4*)(x + (size_t)src * 256 + lane * 4);
  float s1 = v.x + v.y + v.z + v.w;
  float s2 = v.x * v.x + v.y * v.y + v.z * v.z + v.w * v.w;
  #pragma unroll
  for (int d = 1; d < 64; d <<= 1) {
    s1 += __shfl_xor(s1, d);
    s2 += __shfl_xor(s2, d);
  }
  float mu = s1 * (1.f / 256.f);
  float var = s2 * (1.f / 256.f) - mu * mu;
  float rs = rsqrtf(var + 1e-5f);
  const float4 gv = *(const float4*)(g + lane * 4);
  const float4 bv = *(const float4*)(bias + lane * 4);
  ushort4 pk;
  pk.x = bfbits((v.x - mu) * rs * gv.x + bv.x);
  pk.y = bfbits((v.y - mu) * rs * gv.y + bv.y);
  pk.z = bfbits((v.z - mu) * rs * gv.z + bv.z);
  pk.w = bfbits((v.w - mu) * rs * gv.w + bv.w);
  *(ushort4*)((unsigned short*)out + (size_t)t * 256 + lane * 4) = pk;
}

// ---------------- GEMM: C = A[M x K]bf16 @ Bt[N x K]bf16^T + bias, fused epilogues
template<int EPI>
__global__ __launch_bounds__(256) void gemm_k(const bf16* __restrict__ A,
                                              const bf16* __restrict__ Bt,
                                              const float* __restrict__ bias,
                                              int N, int K, int mrow0,
                                              bf16* __restrict__ out_bf,
                                              float* __restrict__ out_f,
                                              const float* __restrict__ add_f) {
  __shared__ bf16 As[128 * 32];
  __shared__ bf16 Bs[128 * 32];
  const int tid = threadIdx.x;
  const int wid = tid >> 6, lane = tid & 63;
  const int row0 = blockIdx.x * 128, col0 = blockIdx.y * 128;
  const int lrow = tid >> 2, lcol = (tid & 3) * 8;
  const int fr = lane & 15, kh = lane >> 4;
  const int wm = (wid >> 1) * 64, wn = (wid & 1) * 64;
  f32x4 zero4 = {0.f, 0.f, 0.f, 0.f};
  f32x4 acc[4][4];
  #pragma unroll
  for (int i = 0; i < 4; ++i)
    #pragma unroll
    for (int j = 0; j < 4; ++j) acc[i][j] = zero4;

  const bf16* aP = A + (size_t)(row0 + lrow) * K + lcol;
  const bf16* bP = Bt + (size_t)(col0 + lrow) * K + lcol;
  bf16* asD = &As[lrow * 32 + lcol];
  bf16* bsD = &Bs[lrow * 32 + lcol];

  for (int k0 = 0; k0 < K; k0 += 32) {
    __syncthreads();
    gld16(aP + k0, asD);
    gld16(aP + (size_t)64 * K + k0, asD + 64 * 32);
    gld16(bP + k0, bsD);
    gld16(bP + (size_t)64 * K + k0, bsD + 64 * 32);
    __syncthreads();
    bf16x8 af[4], bfr[4];
    #pragma unroll
    for (int i = 0; i < 4; ++i)
      af[i] = *(const bf16x8*)&As[(wm + i * 16 + fr) * 32 + kh * 8];
    #pragma unroll
    for (int j = 0; j < 4; ++j)
      bfr[j] = *(const bf16x8*)&Bs[(wn + j * 16 + fr) * 32 + kh * 8];
    #pragma unroll
    for (int i = 0; i < 4; ++i)
      #pragma unroll
      for (int j = 0; j < 4; ++j)
        acc[i][j] = MFMA16(af[i], bfr[j], acc[i][j]);
  }

  #pragma unroll
  for (int i = 0; i < 4; ++i) {
    #pragma unroll
    for (int j = 0; j < 4; ++j) {
      #pragma unroll
      for (int r = 0; r < 4; ++r) {
        int row = row0 + wm + i * 16 + kh * 4 + r;
        int col = col0 + wn + j * 16 + fr;
        float bb = bias[col];
        if (EPI == 0 && col < 256) bb *= 0.17677669529663687f;
        float v = acc[i][j][r] + bb;
        if (EPI == 0) {
          int part = col >> 8, head = (col >> 5) & 7, hd = col & 31;
          int widx = row / 98, n = row - widx * 98;
          size_t off = ((size_t)(part * 512 + widx) * 8 + head) * 3136 + (size_t)n * 32 + hd;
          out_bf[off] = __float2bfloat16(v);
        } else if (EPI == 1) {
          int widx = row / 98, n = row - widx * 98;
          int zd = widx >> 6, zh = (widx >> 3) & 7, zw = widx & 7;
          int ld = n / 49, rem = n - ld * 49, lh = rem / 7, lw = rem - lh * 7;
          int d = zd * 2 + ld, h = zh * 7 + lh, w = zw * 7 + lw;
          int dsrc = (d + 1) & 15;
          int hsrc = h + 3; if (hsrc >= 56) hsrc -= 56;
          int wsrc = w + 3; if (wsrc >= 56) wsrc -= 56;
          size_t tok = (size_t)(dsrc * 56 + hsrc) * 56 + wsrc;
          out_f[tok * 256 + col] = add_f[tok * 256 + col] + v;
        } else if (EPI == 2) {
          float gl = 0.5f * v * (1.0f + erff(v * 0.70710678118654752f));
          out_bf[(size_t)row * 1024 + col] = __float2bfloat16(gl);
        } else {
          size_t ro = (size_t)(mrow0 + row);
          out_f[ro * 256 + col] = add_f[ro * 256 + col] + v;
        }
      }
    }
  }
}

// ---------------- windowed attention: one block per WINDOW, loops all 8 heads.
// No Q/K/V LDS staging: MFMA fragments load directly from global (L1/L2-hot).
// All register arrays compile-time indexed (no scratch).
__global__ __launch_bounds__(256) void attn_k(const bf16* __restrict__ qkv,
                                              const unsigned short* __restrict__ vt,
                                              const unsigned short* __restrict__ bias_bf,
                                              const unsigned short* __restrict__ mask_bf,
                                              bf16* __restrict__ out) {
  __shared__ unsigned short Pl[112 * 128];  // P[row][m], XOR-swizzled
  __shared__ unsigned short bmS[9800];      // mask bf16 [98][100], staged once
  const int tid = threadIdx.x;
  const int widx = blockIdx.x;
  const int wid = tid >> 6, lane = tid & 63;
  const int fr = lane & 15, kh = lane >> 4;
  const int tr0 = wid * 2;
  f32x4 zero4 = {0.f, 0.f, 0.f, 0.f};
  bf16x8 zf = {0, 0, 0, 0, 0, 0, 0, 0};

  const unsigned short* mrow = mask_bf + (size_t)widx * 9604;
  for (int j = tid; j < 4802; j += 256) {
    int n = j / 49, m2 = (j - n * 49) * 2;
    *(unsigned int*)&bmS[n * 100 + m2] = *(const unsigned int*)(mrow + n * 98 + m2);
  }
  __syncthreads();

  for (int head = 0; head < 8; ++head) {
    const unsigned short* qbu = (const unsigned short*)qkv + ((size_t)widx * 8 + head) * 3136;
    const unsigned short* kbu = qbu + (size_t)12845056;
    const unsigned short* brow = bias_bf + head * 9604;
    const unsigned short* vtb = vt + (((size_t)widx * 8 + head) << 12);

    // Q fragments (this wave's 2 row-tiles), K fragments (all 7 m-tiles)
    bf16x8 aq[2];
    #pragma unroll
    for (int ti = 0; ti < 2; ++ti) {
      int tr = tr0 + ti;
      if (tr < 7) {
        int row = tr * 16 + fr; if (row > 97) row = 97;
        aq[ti] = *(const bf16x8*)(qbu + row * 32 + kh * 8);
      } else aq[ti] = zf;
    }
    bf16x8 kf[7];
    #pragma unroll
    for (int mt = 0; mt < 7; ++mt) {
      int row = mt * 16 + fr; if (row > 97) row = 97;
      kf[mt] = *(const bf16x8*)(kbu + row * 32 + kh * 8);
    }

    // QK^T
    f32x4 s[2][7];
    #pragma unroll
    for (int a = 0; a < 2; ++a)
      #pragma unroll
      for (int m = 0; m < 7; ++m) s[a][m] = zero4;
    #pragma unroll
    for (int mt = 0; mt < 7; ++mt) {
      #pragma unroll
      for (int ti = 0; ti < 2; ++ti)
        if (tr0 + ti < 7) s[ti][mt] = MFMA16(aq[ti], kf[mt], s[ti][mt]);
    }

    __syncthreads();   // prev head's PV reads of Pl are done

    // softmax: row lives in an aligned 16-lane group; bias from global (L2-hot),
    // mask from LDS
    #pragma unroll
    for (int ti = 0; ti < 2; ++ti) {
      int tr = tr0 + ti;
      if (tr < 7) {
        #pragma unroll
        for (int r = 0; r < 4; ++r) {
          int row = tr * 16 + kh * 4 + r;
          bool rv = row < 98;
          int rc = rv ? row : 0;
          float vals[7];
          float mx = -1e30f;
          #pragma unroll
          for (int mt = 0; mt < 7; ++mt) {
            int m = mt * 16 + fr;
            float sv = -1e30f;
            if (rv && m < 98)
              sv = s[ti][mt][r] + bf2f(brow[rc * 98 + m]) + bf2f(bmS[rc * 100 + m]);
            vals[mt] = sv;
            mx = fmaxf(mx, sv);
          }
          #pragma unroll
          for (int d = 1; d < 16; d <<= 1) mx = fmaxf(mx, __shfl_xor(mx, d));
          float sum = 0.f;
          float p[7];
          #pragma unroll
          for (int mt = 0; mt < 7; ++mt) {
            float e = (vals[mt] > -1e29f) ? __expf(vals[mt] - mx) : 0.f;
            p[mt] = e; sum += e;
          }
          #pragma unroll
          for (int d = 1; d < 16; d <<= 1) sum += __shfl_xor(sum, d);
          float inv = rv ? (1.0f / sum) : 0.f;
          #pragma unroll
          for (int mt = 0; mt < 7; ++mt) {
            int m = mt * 16 + fr;
            Pl[(row * 128 + m) ^ ((row & 7) << 3)] = bfbits(p[mt] * inv);
          }
          Pl[(row * 128 + 112 + fr) ^ ((row & 7) << 3)] = 0;  // zero tail cols
        }
      }
    }
    __syncthreads();

    // PV: out[row][c] = sum_m P[row][m] * V[m][c]; V^T fragments direct from global
    f32x4 o[2][2];
    #pragma unroll
    for (int a = 0; a < 2; ++a)
      #pragma unroll
      for (int c = 0; c < 2; ++c) o[a][c] = zero4;
    #pragma unroll
    for (int kk = 0; kk < 4; ++kk) {
      bf16x8 vv0 = *(const bf16x8*)(vtb + (0 * 16 + fr) * 128 + kk * 32 + kh * 8);
      bf16x8 vv1 = *(const bf16x8*)(vtb + (1 * 16 + fr) * 128 + kk * 32 + kh * 8);
      #pragma unroll
      for (int ti = 0; ti < 2; ++ti) {
        if (tr0 + ti < 7) {
          int prow = (tr0 + ti) * 16 + fr;
          bf16x8 pa = *(const bf16x8*)&((const bf16*)Pl)[(prow * 128 + kk * 32 + kh * 8) ^ ((prow & 7) << 3)];
          o[ti][0] = MFMA16(pa, vv0, o[ti][0]);
          o[ti][1] = MFMA16(pa, vv1, o[ti][1]);
        }
      }
    }
    #pragma unroll
    for (int ti = 0; ti < 2; ++ti) {
      int tr = tr0 + ti;
      if (tr < 7) {
        #pragma unroll
        for (int ct = 0; ct < 2; ++ct) {
          #pragma unroll
          for (int r = 0; r < 4; ++r) {
            int row = tr * 16 + kh * 4 + r;
            if (row < 98) {
              size_t grow = (size_t)widx * 98 + row;
              int col = head * 32 + ct * 16 + fr;
              out[grow * 256 + col] = __float2bfloat16(o[ti][ct][r]);
            }
          }
        }
      }
    }
  }
}

extern "C" void kernel_launch(void* const* d_in, const int* in_sizes, int n_in,
                              void* d_out, int out_size, void* d_ws, size_t ws_size,
                              hipStream_t stream) {
  const float* x      = (const float*)d_in[0];
  const float* maskM  = (const float*)d_in[1];
  const float* g1     = (const float*)d_in[2];
  const float* b1     = (const float*)d_in[3];
  const float* qkv_w  = (const float*)d_in[4];
  const float* qkv_b  = (const float*)d_in[5];
  const float* rpb    = (const float*)d_in[6];
  const float* proj_w = (const float*)d_in[7];
  const float* proj_b = (const float*)d_in[8];
  const float* g2     = (const float*)d_in[9];
  const float* b2     = (const float*)d_in[10];
  const float* fc1_w  = (const float*)d_in[11];
  const float* fc1_b  = (const float*)d_in[12];
  const float* fc2_w  = (const float*)d_in[13];
  const float* fc2_b  = (const float*)d_in[14];
  float* outp = (float*)d_out;

  char* ws = (char*)d_ws;
  if (ws_size < (size_t)156237824) return;  // need ~149 MB scratch
  bf16*  wqkvT   = (bf16*)(ws + 0);          // 768x256
  bf16*  wprojT  = (bf16*)(ws + 393216);     // 256x256
  bf16*  wfc1T   = (bf16*)(ws + 524288);     // 1024x256
  bf16*  wfc2T   = (bf16*)(ws + 1048576);    // 256x1024
  unsigned short* bias_bf = (unsigned short*)(ws + 1572864);  // 8x9604 bf16
  float* x2      = (float*)(ws + 2097152);   // 50176x256 f32 (written after attn)
  unsigned short* mask_bf = (unsigned short*)(ws + 2097152);  // 512x9604 bf16, aliases x2
  unsigned short* vtb     = (unsigned short*)(ws + 11931648); // 512x8x32x128 bf16, aliases x2 tail
  char*  pool    = ws + 53477376;
  bf16*  xw       = (bf16*)pool;                    // 50176x256 bf16
  bf16*  qkvb     = (bf16*)(pool + 25690112);       // 3x512x8x98x32 bf16
  bf16*  attn_out = (bf16*)pool;                    // reuses xw
  bf16*  hbuf     = (bf16*)pool;                    // reuses attn_out
  bf16*  hh       = (bf16*)(pool + 25690112);       // 25088x1024 bf16 (chunk), reuses qkvb

  transpose_w<<<768, 256, 0, stream>>>(qkv_w, wqkvT, 768, 256, 256, 0.17677669529663687f);
  transpose_w<<<256, 256, 0, stream>>>(proj_w, wprojT, 256, 256, 0, 1.f);
  transpose_w<<<1024, 256, 0, stream>>>(fc1_w, wfc1T, 1024, 256, 0, 1.f);
  transpose_w<<<1024, 256, 0, stream>>>(fc2_w, wfc2T, 256, 1024, 0, 1.f);
  bias_table_bf<<<38, 256, 0, stream>>>(rpb, bias_bf);
  f2bf_k<<<19208, 256, 0, stream>>>(maskM, mask_bf, 512 * 9604);

  ln_k<<<12544, 256, 0, stream>>>(x, g1, b1, xw, 1);
  gemm_k<0><<<dim3(392, 6), 256, 0, stream>>>(xw, wqkvT, qkv_b, 768, 256, 0, qkvb, nullptr, nullptr);
  vtrans_k<<<4096, 256, 0, stream>>>((const unsigned short*)qkvb + (size_t)2 * 12845056, vtb);
  attn_k<<<512, 256, 0, stream>>>(qkvb, vtb, bias_bf, mask_bf, attn_out);
  gemm_k<1><<<dim3(392, 2), 256, 0, stream>>>(attn_out, wprojT, proj_b, 256, 256, 0, nullptr, x2, x);
  ln_k<<<12544, 256, 0, stream>>>(x2, g2, b2, hbuf, 0);
  for (int ch = 0; ch < 2; ++ch) {
    gemm_k<2><<<dim3(196, 8), 256, 0, stream>>>(hbuf + (size_t)ch * 25088 * 256, wfc1T, fc1_b,
                                                1024, 256, 0, hh, nullptr, nullptr);
    gemm_k<3><<<dim3(196, 2), 256, 0, stream>>>(hh, wfc2T, fc2_b, 256, 1024, ch * 25088,
                                                nullptr, outp, x2);
  }
}